// Round 2
// baseline (36.996 us; speedup 1.0000x reference)
//
#include <hip/hip_runtime.h>

// DistanceInfoNCE, algebraically reduced:
//   S[i] = B*sq[i] + sum_sq - 2*dot(a_i, asum) + neg_dist[i]
// Two-kernel pipeline (no init / no finalize kernels):
//   K1: row stats (sq/pd/nd) + per-block column partials C[blk][256] + sq partials.
//       Block 0 zeroes the loss accumulator + done-counter (race-free: only writer).
//   K2: each block redundantly reduces C (256 KB from L2) -> asum slice + sum_sq,
//       then computes per-row loss; last block (fenced atomic counter) writes out.
//
// ws layout (floats):
//   [0]            loss accumulator
//   [1]            done counter (int)
//   [8 .. 8+65536) C[256][256] column partials
//   [P_SQP..+256)  per-block sum-of-squares partials
//   [P_SQ..+B)     sq[B], then pd[B], then nd[B]

#define BLK 256
#define G1 256
#define G2 256
#define NW1 (G1 * 4)
#define NW2 (G2 * 4)

#define P_LOSS 0
#define P_CNT  1
#define P_C    8
#define P_SQP  (P_C + G1 * 256)      // 65544
#define P_SQ   (P_SQP + G1)          // 65800

__device__ __forceinline__ float wave_reduce(float v) {
    #pragma unroll
    for (int off = 32; off > 0; off >>= 1) v += __shfl_down(v, off, 64);
    return v;
}

__global__ void k1_fused(const float4* __restrict__ A, const float4* __restrict__ P,
                         const float4* __restrict__ N, float* __restrict__ ws, int B) {
    const int lane = threadIdx.x & 63;
    const int wid  = threadIdx.x >> 6;
    const int gw   = blockIdx.x * 4 + wid;

    if (blockIdx.x == 0 && threadIdx.x == 0) {
        ws[P_LOSS] = 0.0f;
        ((int*)ws)[P_CNT] = 0;
    }

    float* __restrict__ sq_o = ws + P_SQ;
    float* __restrict__ pd_o = sq_o + B;
    float* __restrict__ nd_o = pd_o + B;

    __shared__ float4 ls4[4][64];
    __shared__ float  sqr[4];

    float4 col = make_float4(0.f, 0.f, 0.f, 0.f);
    float  wsq = 0.0f;

    for (int i = gw; i < B; i += NW1) {
        const float4 a = A[i * 64 + lane];
        const float4 p = P[i * 64 + lane];
        const float4 n = N[i * 64 + lane];
        col.x += a.x; col.y += a.y; col.z += a.z; col.w += a.w;
        const float dpx = a.x - p.x, dpy = a.y - p.y, dpz = a.z - p.z, dpw = a.w - p.w;
        const float dnx = a.x - n.x, dny = a.y - n.y, dnz = a.z - n.z, dnw = a.w - n.w;
        float s_sq = a.x * a.x + a.y * a.y + a.z * a.z + a.w * a.w;
        float s_pd = dpx * dpx + dpy * dpy + dpz * dpz + dpw * dpw;
        float s_nd = dnx * dnx + dny * dny + dnz * dnz + dnw * dnw;
        #pragma unroll
        for (int off = 32; off > 0; off >>= 1) {
            s_sq += __shfl_down(s_sq, off, 64);
            s_pd += __shfl_down(s_pd, off, 64);
            s_nd += __shfl_down(s_nd, off, 64);
        }
        if (lane == 0) {
            sq_o[i] = s_sq;
            pd_o[i] = s_pd;
            nd_o[i] = s_nd;
            wsq += s_sq;
        }
    }

    ls4[wid][lane] = col;
    if (lane == 0) sqr[wid] = wsq;
    __syncthreads();

    // per-thread column combine (conflict-free: consecutive threads -> consecutive banks)
    const float* lsf = (const float*)ls4;  // viewed as [4][256]
    const float c = lsf[0 * 256 + threadIdx.x] + lsf[1 * 256 + threadIdx.x] +
                    lsf[2 * 256 + threadIdx.x] + lsf[3 * 256 + threadIdx.x];
    ws[P_C + blockIdx.x * 256 + threadIdx.x] = c;            // coalesced 1 KB/block
    if (threadIdx.x == 0)
        ws[P_SQP + blockIdx.x] = sqr[0] + sqr[1] + sqr[2] + sqr[3];
}

__global__ void k2_fused(const float4* __restrict__ A, float* __restrict__ ws,
                         float* __restrict__ out, int B) {
    const int lane = threadIdx.x & 63;
    const int wid  = threadIdx.x >> 6;
    const int gw   = blockIdx.x * 4 + wid;

    const float* __restrict__ sq_i = ws + P_SQ;
    const float* __restrict__ pd_i = sq_i + B;
    const float* __restrict__ nd_i = pd_i + B;

    // stage 2: reduce column partials (coalesced float4 rows) + sum_sq
    const float4* __restrict__ C4 = (const float4*)(ws + P_C);  // [G1][64]
    float4 s = make_float4(0.f, 0.f, 0.f, 0.f);
    for (int b = wid; b < G1; b += 4) {
        const float4 v = C4[b * 64 + lane];
        s.x += v.x; s.y += v.y; s.z += v.z; s.w += v.w;
    }
    __shared__ float4 as4[4][64];
    __shared__ float  sred[4];
    as4[wid][lane] = s;

    float v = ws[P_SQP + threadIdx.x];     // G1 == BLK == 256, one partial per thread
    v = wave_reduce(v);
    if (lane == 0) sred[wid] = v;
    __syncthreads();

    const float4 s0 = as4[0][lane], s1 = as4[1][lane], s2 = as4[2][lane], s3 = as4[3][lane];
    s.x = s0.x + s1.x + s2.x + s3.x;
    s.y = s0.y + s1.y + s2.y + s3.y;
    s.z = s0.z + s1.z + s2.z + s3.z;
    s.w = s0.w + s1.w + s2.w + s3.w;
    const float sum_sq = sred[0] + sred[1] + sred[2] + sred[3];
    const float Bf = (float)B;

    float wl = 0.0f;
    for (int i = gw; i < B; i += NW2) {
        const float4 a = A[i * 64 + lane];
        float d = a.x * s.x + a.y * s.y + a.z * s.z + a.w * s.w;
        d = wave_reduce(d);
        if (lane == 0) {
            const float S = Bf * sq_i[i] + sum_sq - 2.0f * d + nd_i[i];
            const float ps = expf(-2.0f * pd_i[i]);   // /TAU, TAU=0.5
            const float ns = expf(-2.0f * S);
            wl += -logf(ps / (ps + ns + 1e-9f));
        }
    }

    __shared__ float lred[4];
    if (lane == 0) lred[wid] = wl;
    __syncthreads();
    if (threadIdx.x == 0) {
        atomicAdd(&ws[P_LOSS], lred[0] + lred[1] + lred[2] + lred[3]);
        __threadfence();
        const int old = atomicAdd((int*)ws + P_CNT, 1);
        if (old == G2 - 1) {
            const float tot = atomicAdd(&ws[P_LOSS], 0.0f);  // coherent read of final sum
            out[0] = tot * (1.0f / Bf);
        }
    }
}

// ---------------- fallback path (small ws): round-1 4-kernel version ----------------

__global__ void k_init(float* __restrict__ ws) {
    for (int i = threadIdx.x; i < 260; i += BLK) ws[i] = 0.0f;
}

__global__ void k_pass1(const float4* __restrict__ A, const float4* __restrict__ P,
                        const float4* __restrict__ N, float* __restrict__ ws, int B) {
    const int lane = threadIdx.x & 63;
    const int wid  = threadIdx.x >> 6;
    const int gwave = blockIdx.x * 4 + wid;

    float* __restrict__ sq_o = ws + 260;
    float* __restrict__ pd_o = ws + 260 + B;
    float* __restrict__ nd_o = ws + 260 + 2 * B;

    __shared__ float lsum[256];
    __shared__ float sqred[4];
    lsum[threadIdx.x] = 0.0f;
    __syncthreads();

    float4 col = make_float4(0.f, 0.f, 0.f, 0.f);
    float wave_sq = 0.0f;

    for (int i = gwave; i < B; i += NW1) {
        const float4 a = A[i * 64 + lane];
        const float4 p = P[i * 64 + lane];
        const float4 n = N[i * 64 + lane];
        col.x += a.x; col.y += a.y; col.z += a.z; col.w += a.w;
        const float dpx = a.x - p.x, dpy = a.y - p.y, dpz = a.z - p.z, dpw = a.w - p.w;
        const float dnx = a.x - n.x, dny = a.y - n.y, dnz = a.z - n.z, dnw = a.w - n.w;
        float s_sq = a.x * a.x + a.y * a.y + a.z * a.z + a.w * a.w;
        float s_pd = dpx * dpx + dpy * dpy + dpz * dpz + dpw * dpw;
        float s_nd = dnx * dnx + dny * dny + dnz * dnz + dnw * dnw;
        #pragma unroll
        for (int off = 32; off > 0; off >>= 1) {
            s_sq += __shfl_down(s_sq, off, 64);
            s_pd += __shfl_down(s_pd, off, 64);
            s_nd += __shfl_down(s_nd, off, 64);
        }
        if (lane == 0) { sq_o[i] = s_sq; pd_o[i] = s_pd; nd_o[i] = s_nd; wave_sq += s_sq; }
    }

    atomicAdd(&lsum[4 * lane + 0], col.x);
    atomicAdd(&lsum[4 * lane + 1], col.y);
    atomicAdd(&lsum[4 * lane + 2], col.z);
    atomicAdd(&lsum[4 * lane + 3], col.w);
    if (lane == 0) sqred[wid] = wave_sq;
    __syncthreads();

    atomicAdd(&ws[4 + threadIdx.x], lsum[threadIdx.x]);
    if (threadIdx.x == 0)
        atomicAdd(&ws[1], sqred[0] + sqred[1] + sqred[2] + sqred[3]);
}

__global__ void k_pass2(const float4* __restrict__ A, float* __restrict__ ws, int B) {
    const int lane = threadIdx.x & 63;
    const int wid  = threadIdx.x >> 6;
    const int gwave = blockIdx.x * 4 + wid;

    const float* __restrict__ sq_i = ws + 260;
    const float* __restrict__ pd_i = ws + 260 + B;
    const float* __restrict__ nd_i = ws + 260 + 2 * B;

    const float sum_sq = ws[1];
    const float4 s = ((const float4*)(ws + 4))[lane];
    const float Bf = (float)B;

    float wave_loss = 0.0f;
    for (int i = gwave; i < B; i += NW2) {
        const float4 a = A[i * 64 + lane];
        float d = a.x * s.x + a.y * s.y + a.z * s.z + a.w * s.w;
        d = wave_reduce(d);
        if (lane == 0) {
            const float S = Bf * sq_i[i] + sum_sq - 2.0f * d + nd_i[i];
            const float ps = expf(-2.0f * pd_i[i]);
            const float ns = expf(-2.0f * S);
            wave_loss += -logf(ps / (ps + ns + 1e-9f));
        }
    }

    __shared__ float lred[4];
    if (lane == 0) lred[wid] = wave_loss;
    __syncthreads();
    if (threadIdx.x == 0)
        atomicAdd(&ws[0], lred[0] + lred[1] + lred[2] + lred[3]);
}

__global__ void k_fin(const float* __restrict__ ws, float* __restrict__ out, float invB) {
    out[0] = ws[0] * invB;
}

extern "C" void kernel_launch(void* const* d_in, const int* in_sizes, int n_in,
                              void* d_out, int out_size, void* d_ws, size_t ws_size,
                              hipStream_t stream) {
    const float4* A = (const float4*)d_in[0];
    const float4* P = (const float4*)d_in[1];
    const float4* N = (const float4*)d_in[2];
    float* ws  = (float*)d_ws;
    float* out = (float*)d_out;
    const int D = 256;
    const int B = in_sizes[0] / D;   // 4096

    const size_t need = (size_t)(P_SQ + 3 * B) * sizeof(float);  // ~312 KB
    if (ws_size >= need && B == 4096) {
        k1_fused<<<G1, BLK, 0, stream>>>(A, P, N, ws, B);
        k2_fused<<<G2, BLK, 0, stream>>>(A, ws, out, B);
    } else {
        k_init <<<1, BLK, 0, stream>>>(ws);
        k_pass1<<<G1, BLK, 0, stream>>>(A, P, N, ws, B);
        k_pass2<<<G2, BLK, 0, stream>>>(A, ws, B);
        k_fin  <<<1, 1, 0, stream>>>(ws, out, 1.0f / (float)B);
    }
}

// Round 3
// 32.062 us; speedup vs baseline: 1.1539x; 1.1539x over previous
//
#include <hip/hip_runtime.h>

// DistanceInfoNCE, algebraically reduced:
//   S[i] = B*sq[i] + sum_sq - 2*dot(a_i, asum) + neg_dist[i]
//
// Single resident-grid kernel + spin barrier (256 blocks = 1/CU, co-resident):
//   Phase A: each wave owns 4 rows; loads a,p,n; keeps a[] and row stats in
//            REGISTERS; block-combines column sums in LDS; atomicAdd into one
//            of 32 global partial sets (32 KB, low contention).
//   Grid barrier (device-scope atomic counter + acquire spin).
//   Phase B: each block reduces the 32 sets (32 KB) -> asum + sum_sq, computes
//            per-row loss from registers, last-arriving block writes the mean.
// A tiny k_zero kernel re-zeroes counters/accumulators every replay (ws is
// poisoned 0xAA once and never restored, and our atomics accumulate).
//
// ws float layout:
//   [0] loss  [1] cnt(int)  [2] cnt2(int)  [8..40) per-set sq partials
//   [64 .. 64+32*256) Cpart[32][256]

#define BLK   256
#define GRID  256
#define NSETS 32

#define W_LOSS 0
#define W_CNT  1
#define W_CNT2 2
#define W_SQP  8
#define W_CP   64

__device__ __forceinline__ float wave_reduce(float v) {
    #pragma unroll
    for (int off = 32; off > 0; off >>= 1) v += __shfl_down(v, off, 64);
    return v;
}

__global__ void k_zero(float* __restrict__ ws) {
    const int t = blockIdx.x * BLK + threadIdx.x;   // grid 32 -> t in [0,8192)
    ws[W_CP + t] = 0.0f;
    if (t < 64) ws[t] = 0.0f;                       // loss, cnt, cnt2, sq partials
}

__global__ __launch_bounds__(BLK, 1)
void k_main(const float4* __restrict__ A, const float4* __restrict__ P,
            const float4* __restrict__ N, float* ws, float* __restrict__ out, int B) {
    const int lane = threadIdx.x & 63;
    const int wid  = threadIdx.x >> 6;
    const int gw   = blockIdx.x * 4 + wid;          // 1024 waves, 4 rows each
    const float Bf = (float)B;

    // ---------------- Phase A: row stats + column partials ----------------
    float4 a[4];
    float  ssq[4], spd[4], snd[4];                  // valid in lane 0 after reduce
    float4 col = make_float4(0.f, 0.f, 0.f, 0.f);
    float  wsq = 0.0f;
    const int base = gw * 4;

    #pragma unroll
    for (int r = 0; r < 4; ++r) {
        const int i = base + r;
        a[r] = A[i * 64 + lane];
        const float4 p = P[i * 64 + lane];
        const float4 n = N[i * 64 + lane];
        col.x += a[r].x; col.y += a[r].y; col.z += a[r].z; col.w += a[r].w;
        const float dpx = a[r].x - p.x, dpy = a[r].y - p.y, dpz = a[r].z - p.z, dpw = a[r].w - p.w;
        const float dnx = a[r].x - n.x, dny = a[r].y - n.y, dnz = a[r].z - n.z, dnw = a[r].w - n.w;
        float s_sq = a[r].x * a[r].x + a[r].y * a[r].y + a[r].z * a[r].z + a[r].w * a[r].w;
        float s_pd = dpx * dpx + dpy * dpy + dpz * dpz + dpw * dpw;
        float s_nd = dnx * dnx + dny * dny + dnz * dnz + dnw * dnw;
        #pragma unroll
        for (int off = 32; off > 0; off >>= 1) {
            s_sq += __shfl_down(s_sq, off, 64);
            s_pd += __shfl_down(s_pd, off, 64);
            s_nd += __shfl_down(s_nd, off, 64);
        }
        ssq[r] = s_sq; spd[r] = s_pd; snd[r] = s_nd;
        if (lane == 0) wsq += s_sq;
    }

    __shared__ float4 ls4[4][64];
    __shared__ float  sqr[4];
    ls4[wid][lane] = col;
    if (lane == 0) sqr[wid] = wsq;
    __syncthreads();

    const float* lsf = (const float*)ls4;           // [4][256] view
    const float c = lsf[threadIdx.x] + lsf[256 + threadIdx.x] +
                    lsf[512 + threadIdx.x] + lsf[768 + threadIdx.x];
    const int set = blockIdx.x & (NSETS - 1);
    atomicAdd(&ws[W_CP + set * 256 + threadIdx.x], c);
    if (threadIdx.x == 0)
        atomicAdd(&ws[W_SQP + set], sqr[0] + sqr[1] + sqr[2] + sqr[3]);

    // ---------------- grid barrier (all 256 blocks co-resident) ----------------
    __syncthreads();                                // drains this block's vmem (atomics)
    if (threadIdx.x == 0) {
        __threadfence();
        atomicAdd((int*)ws + W_CNT, 1);
        while (__hip_atomic_load((int*)ws + W_CNT, __ATOMIC_ACQUIRE,
                                 __HIP_MEMORY_SCOPE_AGENT) < GRID) {
            __builtin_amdgcn_s_sleep(1);
        }
        __threadfence();
    }
    __syncthreads();

    // ---------------- Phase B: asum + sum_sq, then loss ----------------
    float asum_t = 0.0f;
    #pragma unroll
    for (int s = 0; s < NSETS; ++s) asum_t += ws[W_CP + s * 256 + threadIdx.x];
    float sum_sq = 0.0f;
    #pragma unroll
    for (int s = 0; s < NSETS; ++s) sum_sq += ws[W_SQP + s];   // uniform -> scalar loads

    __shared__ float lds_asum[256];
    lds_asum[threadIdx.x] = asum_t;
    __syncthreads();
    const float4 frag = *(const float4*)&lds_asum[lane * 4];

    float wl = 0.0f;
    #pragma unroll
    for (int r = 0; r < 4; ++r) {
        float d = a[r].x * frag.x + a[r].y * frag.y + a[r].z * frag.z + a[r].w * frag.w;
        d = wave_reduce(d);
        if (lane == 0) {
            const float S  = Bf * ssq[r] + sum_sq - 2.0f * d + snd[r];
            const float ps = expf(-2.0f * spd[r]);   // /TAU, TAU=0.5
            const float ns = expf(-2.0f * S);
            wl += -logf(ps / (ps + ns + 1e-9f));
        }
    }

    __shared__ float lred[4];
    if (lane == 0) lred[wid] = wl;
    __syncthreads();
    if (threadIdx.x == 0) {
        atomicAdd(&ws[W_LOSS], lred[0] + lred[1] + lred[2] + lred[3]);
        __threadfence();
        const int old = atomicAdd((int*)ws + W_CNT2, 1);
        if (old == GRID - 1) {
            const float tot = __hip_atomic_load(&ws[W_LOSS], __ATOMIC_ACQUIRE,
                                                __HIP_MEMORY_SCOPE_AGENT);
            out[0] = tot * (1.0f / Bf);
        }
    }
}

// ---------------- fallback (B not a multiple of 1024): round-1 pipeline ----------------

__global__ void k_init(float* __restrict__ ws) {
    for (int i = threadIdx.x; i < 260; i += BLK) ws[i] = 0.0f;
}

__global__ void k_pass1(const float4* __restrict__ A, const float4* __restrict__ P,
                        const float4* __restrict__ N, float* __restrict__ ws, int B) {
    const int lane = threadIdx.x & 63;
    const int wid  = threadIdx.x >> 6;
    const int gwave = blockIdx.x * 4 + wid;

    float* __restrict__ sq_o = ws + 260;
    float* __restrict__ pd_o = ws + 260 + B;
    float* __restrict__ nd_o = ws + 260 + 2 * B;

    __shared__ float lsum[256];
    __shared__ float sqred[4];
    lsum[threadIdx.x] = 0.0f;
    __syncthreads();

    float4 col = make_float4(0.f, 0.f, 0.f, 0.f);
    float wave_sq = 0.0f;

    for (int i = gwave; i < B; i += GRID * 4) {
        const float4 a = A[i * 64 + lane];
        const float4 p = P[i * 64 + lane];
        const float4 n = N[i * 64 + lane];
        col.x += a.x; col.y += a.y; col.z += a.z; col.w += a.w;
        const float dpx = a.x - p.x, dpy = a.y - p.y, dpz = a.z - p.z, dpw = a.w - p.w;
        const float dnx = a.x - n.x, dny = a.y - n.y, dnz = a.z - n.z, dnw = a.w - n.w;
        float s_sq = a.x * a.x + a.y * a.y + a.z * a.z + a.w * a.w;
        float s_pd = dpx * dpx + dpy * dpy + dpz * dpz + dpw * dpw;
        float s_nd = dnx * dnx + dny * dny + dnz * dnz + dnw * dnw;
        #pragma unroll
        for (int off = 32; off > 0; off >>= 1) {
            s_sq += __shfl_down(s_sq, off, 64);
            s_pd += __shfl_down(s_pd, off, 64);
            s_nd += __shfl_down(s_nd, off, 64);
        }
        if (lane == 0) { sq_o[i] = s_sq; pd_o[i] = s_pd; nd_o[i] = s_nd; wave_sq += s_sq; }
    }

    atomicAdd(&lsum[4 * lane + 0], col.x);
    atomicAdd(&lsum[4 * lane + 1], col.y);
    atomicAdd(&lsum[4 * lane + 2], col.z);
    atomicAdd(&lsum[4 * lane + 3], col.w);
    if (lane == 0) sqred[wid] = wave_sq;
    __syncthreads();

    atomicAdd(&ws[4 + threadIdx.x], lsum[threadIdx.x]);
    if (threadIdx.x == 0)
        atomicAdd(&ws[1], sqred[0] + sqred[1] + sqred[2] + sqred[3]);
}

__global__ void k_pass2(const float4* __restrict__ A, float* __restrict__ ws, int B) {
    const int lane = threadIdx.x & 63;
    const int wid  = threadIdx.x >> 6;
    const int gwave = blockIdx.x * 4 + wid;

    const float* __restrict__ sq_i = ws + 260;
    const float* __restrict__ pd_i = ws + 260 + B;
    const float* __restrict__ nd_i = ws + 260 + 2 * B;

    const float sum_sq = ws[1];
    const float4 s = ((const float4*)(ws + 4))[lane];
    const float Bf = (float)B;

    float wave_loss = 0.0f;
    for (int i = gwave; i < B; i += GRID * 4) {
        const float4 a = A[i * 64 + lane];
        float d = a.x * s.x + a.y * s.y + a.z * s.z + a.w * s.w;
        d = wave_reduce(d);
        if (lane == 0) {
            const float S = Bf * sq_i[i] + sum_sq - 2.0f * d + nd_i[i];
            const float ps = expf(-2.0f * pd_i[i]);
            const float ns = expf(-2.0f * S);
            wave_loss += -logf(ps / (ps + ns + 1e-9f));
        }
    }

    __shared__ float lred[4];
    if (lane == 0) lred[wid] = wave_loss;
    __syncthreads();
    if (threadIdx.x == 0)
        atomicAdd(&ws[0], lred[0] + lred[1] + lred[2] + lred[3]);
}

__global__ void k_fin(const float* __restrict__ ws, float* __restrict__ out, float invB) {
    out[0] = ws[0] * invB;
}

extern "C" void kernel_launch(void* const* d_in, const int* in_sizes, int n_in,
                              void* d_out, int out_size, void* d_ws, size_t ws_size,
                              hipStream_t stream) {
    const float4* A = (const float4*)d_in[0];
    const float4* P = (const float4*)d_in[1];
    const float4* N = (const float4*)d_in[2];
    float* ws  = (float*)d_ws;
    float* out = (float*)d_out;
    const int D = 256;
    const int B = in_sizes[0] / D;   // 4096

    const size_t need = (size_t)(W_CP + NSETS * 256) * sizeof(float);  // ~33 KB
    if (B == (GRID * 4 * 4) / 4 && (B & 1023) == 0 && ws_size >= need) {
        k_zero<<<NSETS, BLK, 0, stream>>>(ws);
        k_main<<<GRID, BLK, 0, stream>>>(A, P, N, ws, out, B);
    } else {
        k_init <<<1, BLK, 0, stream>>>(ws);
        k_pass1<<<GRID, BLK, 0, stream>>>(A, P, N, ws, B);
        k_pass2<<<GRID, BLK, 0, stream>>>(A, ws, B);
        k_fin  <<<1, 1, 0, stream>>>(ws, out, 1.0f / (float)B);
    }
}